// Round 6
// baseline (79.754 us; speedup 1.0000x reference)
//
#include <hip/hip_runtime.h>
#include <float.h>
#include <limits.h>

#define N_ROWS 8192
#define D_COLS 4096
#define RANK_BLOCKS 512

typedef float f32x4 __attribute__((ext_vector_type(4)));

// Kernel 1: Err[row] = sum_j (in[row][j] - tg[row][j])^2
// One wave per row, nontemporal loads (read-once stream, skip cache alloc).
// Block 0 also resets the ticket counter for kernel 2 (fresh each launch).
__global__ __launch_bounds__(256) void row_sqerr_kernel(
    const float* __restrict__ in, const float* __restrict__ tg,
    float* __restrict__ err, int* __restrict__ counter) {
  if (blockIdx.x == 0 && threadIdx.x == 0) *counter = 0;
  const int row = (blockIdx.x << 2) | (threadIdx.x >> 6);
  const int lane = threadIdx.x & 63;
  const f32x4* a = (const f32x4*)(in + (size_t)row * D_COLS) + lane;
  const f32x4* b = (const f32x4*)(tg + (size_t)row * D_COLS) + lane;

  float acc0 = 0.f, acc1 = 0.f, acc2 = 0.f, acc3 = 0.f;
  f32x4 xa[8], xb[8];

#pragma unroll
  for (int s = 0; s < 2; ++s) {
#pragma unroll
    for (int p = 0; p < 8; ++p) xa[p] = __builtin_nontemporal_load(&a[(s * 8 + p) * 64]);
#pragma unroll
    for (int p = 0; p < 8; ++p) xb[p] = __builtin_nontemporal_load(&b[(s * 8 + p) * 64]);
#pragma unroll
    for (int p = 0; p < 8; ++p) {
      f32x4 d = xa[p] - xb[p];
      acc0 += d.x * d.x;
      acc1 += d.y * d.y;
      acc2 += d.z * d.z;
      acc3 += d.w * d.w;
    }
  }
  float acc = (acc0 + acc1) + (acc2 + acc3);
#pragma unroll
  for (int off = 32; off > 0; off >>= 1) acc += __shfl_down(acc, off);
  if (lane == 0) err[row] = acc;
}

// Kernel 2: brute-force rank sort (bijective rank -> scatter), then the block
// that takes the LAST ticket (device-scope atomic + threadfence, standard
// last-block pattern, no co-residency assumption) runs the scan+select tail
// in-kernel: prefix sums of sorted errs (f64), split objective, argmin, loss.
__global__ __launch_bounds__(256) void rank_select_kernel(
    const float* __restrict__ err, float* __restrict__ sorted,
    int* __restrict__ counter, float* __restrict__ out) {
  __shared__ float s[N_ROWS];
  const int t = threadIdx.x;

  // stage all 8192 errs into LDS (vectorized, coalesced)
  f32x4* s4w = (f32x4*)s;
  const f32x4* e4 = (const f32x4*)err;
#pragma unroll
  for (int k = 0; k < 8; ++k) s4w[t + (k << 8)] = e4[t + (k << 8)];
  __syncthreads();

  // 16 lanes per element; lane-group g scans a 512-float segment
  const int g = t & 15;
  const int le = t >> 4;
  const int e = (blockIdx.x << 4) | le;
  const float v = s[e];
  const f32x4* s4 = (const f32x4*)s;

  int cnt = 0;
#pragma unroll 8
  for (int k = 0; k < 128; ++k) {
    const int i4 = (g << 7) | ((k + g) & 127);
    const f32x4 c = s4[i4];
    const int j = i4 << 2;
    cnt += (c.x < v) || (c.x == v && (j + 0) < e);
    cnt += (c.y < v) || (c.y == v && (j + 1) < e);
    cnt += (c.z < v) || (c.z == v && (j + 2) < e);
    cnt += (c.w < v) || (c.w == v && (j + 3) < e);
  }
#pragma unroll
  for (int off = 1; off < 16; off <<= 1) cnt += __shfl_xor(cnt, off);
  if (g == 0) sorted[cnt] = v;

  // ---- last-block ticket ----
  __syncthreads();              // drain all waves' scatter writes (vmcnt(0))
  __shared__ int islast;
  if (t == 0) {
    __threadfence();            // release: L2 writeback, device visibility
    islast = (atomicAdd(counter, 1) == RANK_BLOCKS - 1);
  }
  __syncthreads();
  if (!islast) return;
  __threadfence();              // acquire: invalidate stale cache lines

  // ---- tail: scan + select, 256 threads x 32 elements ----
  const f32x4* so4 = (const f32x4*)sorted;
  float vals[32];
  double lsum = 0.0, lsq = 0.0;
#pragma unroll
  for (int k = 0; k < 8; ++k) {
    f32x4 v4 = so4[t * 8 + k];
#pragma unroll
    for (int c = 0; c < 4; ++c) {
      float x = v4[c];
      vals[k * 4 + c] = x;
      lsum += (double)x;
      lsq += (double)x * (double)x;
    }
  }
  const int lane = t & 63, wid = t >> 6;

  // wave inclusive scan of (lsum, lsq)
  double ssum = lsum, ssq = lsq;
#pragma unroll
  for (int off = 1; off < 64; off <<= 1) {
    double u = __shfl_up(ssum, off);
    double uq = __shfl_up(ssq, off);
    if (lane >= off) { ssum += u; ssq += uq; }
  }
  __shared__ double cws[4], cwq[4], ctot[2];
  if (lane == 63) { cws[wid] = ssum; cwq[wid] = ssq; }
  __syncthreads();
  if (t == 0) {
    double a = 0.0, b = 0.0;
#pragma unroll
    for (int w = 0; w < 4; ++w) {
      double x = cws[w], y = cwq[w];
      cws[w] = a; cwq[w] = b;
      a += x; b += y;
    }
    ctot[0] = a; ctot[1] = b;
  }
  __syncthreads();

  double c1 = cws[wid] + (ssum - lsum);  // exclusive prefix before elem t*32
  double q1 = cwq[wid] + (ssq - lsq);
  const double total = ctot[0], total_sq = ctot[1];
  const double nf = (double)N_ROWS;
  const double all_mean = total / nf;
  const double inv_Sb = 1.0 / (total_sq - nf * all_mean * all_mean);

  double best = DBL_MAX;
  int bidx = INT_MAX;
  double bc1 = 0.0;
#pragma unroll
  for (int k = 0; k < 32; ++k) {
    int i = t * 32 + k;
    double v2 = (double)vals[k];
    c1 += v2;
    q1 += v2 * v2;
    if (i <= N_ROWS - 2) {
      double n1 = (double)(i + 1);
      double n2 = nf - n1;
      double mean1 = c1 / n1;
      double mean2 = (total - c1) / n2;
      double Sw1 = q1 - n1 * mean1 * mean1;
      double Sw2 = (total_sq - q1) - n2 * mean2 * mean2;
      double obj = (Sw1 + Sw2) * inv_Sb;
      if (obj < best) { best = obj; bidx = i; bc1 = c1; }
    }
  }

  // wave argmin (lexicographic (obj, idx))
#pragma unroll
  for (int off = 1; off < 64; off <<= 1) {
    double o2 = __shfl_xor(best, off);
    int i2 = __shfl_xor(bidx, off);
    double c2 = __shfl_xor(bc1, off);
    if (o2 < best || (o2 == best && i2 < bidx)) { best = o2; bidx = i2; bc1 = c2; }
  }
  __shared__ double cro[4], crc[4];
  __shared__ int cri[4];
  if (lane == 0) { cro[wid] = best; cri[wid] = bidx; crc[wid] = bc1; }
  __syncthreads();
  if (t == 0) {
    double o = cro[0];
    int bi = cri[0];
    double c = crc[0];
#pragma unroll
    for (int w = 1; w < 4; ++w) {
      if (cro[w] < o || (cro[w] == o && cri[w] < bi)) { o = cro[w]; bi = cri[w]; c = crc[w]; }
    }
    out[0] = (float)(c / (double)(bi + 1) + 0.1 * o);
  }
}

extern "C" void kernel_launch(void* const* d_in, const int* in_sizes, int n_in,
                              void* d_out, int out_size, void* d_ws, size_t ws_size,
                              hipStream_t stream) {
  const float* input = (const float*)d_in[0];
  const float* target = (const float*)d_in[1];
  float* out = (float*)d_out;
  float* err = (float*)d_ws;                       // 8192 floats
  float* sorted = (float*)d_ws + N_ROWS;           // 8192 floats
  int* counter = (int*)((float*)d_ws + 2 * N_ROWS);

  row_sqerr_kernel<<<N_ROWS / 4, 256, 0, stream>>>(input, target, err, counter);
  rank_select_kernel<<<RANK_BLOCKS, 256, 0, stream>>>(err, sorted, counter, out);
}